// Round 10
// baseline (280.075 us; speedup 1.0000x reference)
//
#include <hip/hip_runtime.h>

#define LSEQ 4096
#define DMODEL 1024
#define HTOT 16
#define NAR 8
#define DHEAD 64
#define QKVS 3072  // fused QKV row stride

typedef unsigned short u16;
typedef unsigned int u32;
typedef __attribute__((ext_vector_type(8))) short bf16x8;
typedef __attribute__((ext_vector_type(4))) short bf16x4;
typedef __attribute__((ext_vector_type(4))) float f32x4;
typedef __attribute__((ext_vector_type(4))) unsigned int u32x4;

typedef __attribute__((address_space(1))) void gvoid;
typedef __attribute__((address_space(3))) void lvoid;

__device__ __forceinline__ void cp16(const void* g, void* l) {
    // async global->LDS, 16B per lane; LDS dest = wave-uniform base + lane*16
    __builtin_amdgcn_global_load_lds((gvoid*)(void*)g, (lvoid*)l, 16, 0, 0);
}

__device__ __forceinline__ float bfs(u16 v) { return __uint_as_float((u32)v << 16); }
// round-to-nearest-even fp32 -> bf16
__device__ __forceinline__ u16 f2bf(float f) {
    u32 x = __float_as_uint(f);
    return (u16)((x + 0x7fffu + ((x >> 16) & 1u)) >> 16);
}
// truncation-pack two fp32 -> packed bf16x2 (1 v_perm_b32)
__device__ __forceinline__ u32 packtr(float lo, float hi) {
    return __builtin_amdgcn_perm(__float_as_uint(hi), __float_as_uint(lo), 0x07060302u);
}

// ---------------------------------------------------------------------------
// Fused transpose of Wq/Wk/Wv: 1024x1024 fp32 -> bf16 (D = S^T), z selects.
// ---------------------------------------------------------------------------
__global__ __launch_bounds__(256) void transp_cvt3(
    const float* __restrict__ Wq, const float* __restrict__ Wk,
    const float* __restrict__ Wv, u16* __restrict__ D)
{
    __shared__ u16 T[64][72];
    const float* S = (blockIdx.z == 0) ? Wq : ((blockIdx.z == 1) ? Wk : Wv);
    u16* Dz = D + (size_t)blockIdx.z * 1024 * 1024;
    const int tid = threadIdx.x;
    const int bx = blockIdx.x, by = blockIdx.y;
#pragma unroll
    for (int i = 0; i < 4; ++i) {
        int id = tid + i * 256;
        int fr = id >> 4, fc = id & 15;
        float4 v = *(const float4*)(S + (size_t)(by * 64 + fr) * 1024 + bx * 64 + fc * 4);
        T[fc * 4 + 0][fr] = f2bf(v.x);
        T[fc * 4 + 1][fr] = f2bf(v.y);
        T[fc * 4 + 2][fr] = f2bf(v.z);
        T[fc * 4 + 3][fr] = f2bf(v.w);
    }
    __syncthreads();
#pragma unroll
    for (int i = 0; i < 2; ++i) {
        int id = tid + i * 256;
        int c = id >> 3, g = id & 7;
        *(uint4*)(Dz + (size_t)(bx * 64 + c) * 1024 + by * 64 + g * 8) = *(const uint4*)&T[c][g * 8];
    }
}

// single-matrix version for Wo
__global__ __launch_bounds__(256) void transp_cvt(
    const float* __restrict__ S, u16* __restrict__ D)
{
    __shared__ u16 T[64][72];
    const int tid = threadIdx.x;
    const int bx = blockIdx.x, by = blockIdx.y;
#pragma unroll
    for (int i = 0; i < 4; ++i) {
        int id = tid + i * 256;
        int fr = id >> 4, fc = id & 15;
        float4 v = *(const float4*)(S + (size_t)(by * 64 + fr) * 1024 + bx * 64 + fc * 4);
        T[fc * 4 + 0][fr] = f2bf(v.x);
        T[fc * 4 + 1][fr] = f2bf(v.y);
        T[fc * 4 + 2][fr] = f2bf(v.z);
        T[fc * 4 + 3][fr] = f2bf(v.w);
    }
    __syncthreads();
#pragma unroll
    for (int i = 0; i < 2; ++i) {
        int id = tid + i * 256;
        int c = id >> 3, g = id & 7;
        *(uint4*)(D + (size_t)(bx * 64 + c) * 1024 + by * 64 + g * 8) = *(const uint4*)&T[c][g * 8];
    }
}

// ---------------------------------------------------------------------------
// QKV = X @ [Wq|Wk|Wv] + FUSED RoPE epilogue. A fp32 (trunc-packed to bf16),
// Bt bf16 k-major, C bf16. 128x128 tile, BK=32, dbuf LDS, one barrier/K-step.
// ---------------------------------------------------------------------------
__global__ __launch_bounds__(256) void gemm_qkv(
    const float* __restrict__ A, const u16* __restrict__ Bt, u16* __restrict__ C)
{
    __shared__ u16 As[2][128][40];
    __shared__ u16 Bs[2][128][32];
    const int tid = threadIdx.x;
    const int lane = tid & 63, w = tid >> 6;
    const int col = lane & 15, quad = lane >> 4;
    const int bm = blockIdx.y << 7, bn = blockIdx.x << 7;
    const int wm = (w & 1) << 6, wn = (w >> 1) << 6;
    const int sr = lane >> 2, sc = (lane & 3) << 3;
    const int ar0 = tid >> 2, ag = (tid & 3) << 3;
    const f32x4 zero = {0.f, 0.f, 0.f, 0.f};
    f32x4 acc[4][4];
#pragma unroll
    for (int i = 0; i < 4; ++i)
#pragma unroll
        for (int j = 0; j < 4; ++j) acc[i][j] = zero;

    {
#pragma unroll
        for (int i = 0; i < 2; ++i)
            cp16(Bt + (size_t)(bn + w * 32 + i * 16 + sr) * 1024 + sc, &Bs[0][w * 32 + i * 16][0]);
#pragma unroll
        for (int it = 0; it < 2; ++it) {
            const float* ap = A + (size_t)(bm + ar0 + it * 64) * 1024 + ag;
            float4 a0 = *(const float4*)ap;
            float4 a1 = *(const float4*)(ap + 4);
            uint4 pk;
            pk.x = packtr(a0.x, a0.y); pk.y = packtr(a0.z, a0.w);
            pk.z = packtr(a1.x, a1.y); pk.w = packtr(a1.z, a1.w);
            *(uint4*)&As[0][ar0 + it * 64][ag] = pk;
        }
    }

    for (int kc = 0; kc < 32; ++kc) {
        const int cur = kc & 1, nxt = cur ^ 1;
        __syncthreads();
        const bool pre = (kc + 1 < 32);
        float4 a0[2], a1[2];
        if (pre) {
            const int k1 = (kc + 1) * 32;
#pragma unroll
            for (int i = 0; i < 2; ++i)
                cp16(Bt + (size_t)(bn + w * 32 + i * 16 + sr) * 1024 + k1 + sc,
                     &Bs[nxt][w * 32 + i * 16][0]);
#pragma unroll
            for (int it = 0; it < 2; ++it) {
                const float* ap = A + (size_t)(bm + ar0 + it * 64) * 1024 + k1 + ag;
                a0[it] = *(const float4*)ap;
                a1[it] = *(const float4*)(ap + 4);
            }
        }
        bf16x8 af[4], bfr[4];
#pragma unroll
        for (int i = 0; i < 4; ++i) af[i] = *(const bf16x8*)&As[cur][wm + i * 16 + col][quad * 8];
#pragma unroll
        for (int j = 0; j < 4; ++j) bfr[j] = *(const bf16x8*)&Bs[cur][wn + j * 16 + col][quad * 8];
#pragma unroll
        for (int i = 0; i < 4; ++i)
#pragma unroll
            for (int j = 0; j < 4; ++j)
                acc[i][j] = __builtin_amdgcn_mfma_f32_16x16x32_bf16(af[i], bfr[j], acc[i][j], 0, 0, 0);
        if (pre) {
#pragma unroll
            for (int it = 0; it < 2; ++it) {
                uint4 pk;
                pk.x = packtr(a0[it].x, a0[it].y); pk.y = packtr(a0[it].z, a0[it].w);
                pk.z = packtr(a1[it].x, a1[it].y); pk.w = packtr(a1[it].z, a1[it].w);
                *(uint4*)&As[nxt][ar0 + it * 64][ag] = pk;
            }
        }
    }

    // fused RoPE epilogue (Q and K blocks only)
    if (blockIdx.x < 16) {
        const float scale = (blockIdx.x < 8) ? 0.18033688011112042f : 1.0f;  // Q: (1/8)*log2e
        const float inv0 = __expf((float)col * -0.2878231366242557f);
        const float inv1 = __expf((float)(16 + col) * -0.2878231366242557f);
#pragma unroll
        for (int i = 0; i < 4; ++i)
#pragma unroll
            for (int r = 0; r < 4; ++r) {
                const float t = (float)(bm + wm + i * 16 + quad * 4 + r);
                float s0, c0, s1, c1;
                __sincosf(t * inv0, &s0, &c0);
                __sincosf(t * inv1, &s1, &c1);
                float a0 = acc[i][0][r], b0 = acc[i][2][r];
                acc[i][0][r] = (a0 * c0 - b0 * s0) * scale;
                acc[i][2][r] = (b0 * c0 + a0 * s0) * scale;
                float a1 = acc[i][1][r], b1 = acc[i][3][r];
                acc[i][1][r] = (a1 * c1 - b1 * s1) * scale;
                acc[i][3][r] = (b1 * c1 + a1 * s1) * scale;
            }
    }
#pragma unroll
    for (int i = 0; i < 4; ++i)
#pragma unroll
        for (int j = 0; j < 4; ++j)
#pragma unroll
            for (int r = 0; r < 4; ++r)
                C[(size_t)(bm + wm + i * 16 + quad * 4 + r) * QKVS + bn + wn + j * 16 + col] =
                    f2bf(acc[i][j][r]);
}

// ---------------------------------------------------------------------------
// out = AO @ Wot^T  (both bf16 k-major, C fp32). Dbuf, one barrier/K-step.
// ---------------------------------------------------------------------------
__global__ __launch_bounds__(256) void gemm_out(
    const u16* __restrict__ A, const u16* __restrict__ Bt, float* __restrict__ C)
{
    __shared__ u16 As[2][128][32];
    __shared__ u16 Bs[2][128][32];
    const int tid = threadIdx.x;
    const int lane = tid & 63, w = tid >> 6;
    const int col = lane & 15, quad = lane >> 4;
    const int bm = blockIdx.y << 7, bn = blockIdx.x << 7;
    const int wm = (w & 1) << 6, wn = (w >> 1) << 6;
    const int sr = lane >> 2, sc = (lane & 3) << 3;
    const f32x4 zero = {0.f, 0.f, 0.f, 0.f};
    f32x4 acc[4][4];
#pragma unroll
    for (int i = 0; i < 4; ++i)
#pragma unroll
        for (int j = 0; j < 4; ++j) acc[i][j] = zero;

#pragma unroll
    for (int i = 0; i < 2; ++i) {
        const int r0 = w * 32 + i * 16;
        cp16(A  + (size_t)(bm + r0 + sr) * 1024 + sc, &As[0][r0][0]);
        cp16(Bt + (size_t)(bn + r0 + sr) * 1024 + sc, &Bs[0][r0][0]);
    }

    for (int kc = 0; kc < 32; ++kc) {
        const int cur = kc & 1, nxt = cur ^ 1;
        __syncthreads();
        if (kc + 1 < 32) {
            const int k1 = (kc + 1) * 32;
#pragma unroll
            for (int i = 0; i < 2; ++i) {
                const int r0 = w * 32 + i * 16;
                cp16(A  + (size_t)(bm + r0 + sr) * 1024 + k1 + sc, &As[nxt][r0][0]);
                cp16(Bt + (size_t)(bn + r0 + sr) * 1024 + k1 + sc, &Bs[nxt][r0][0]);
            }
        }
        bf16x8 af[4], bfr[4];
#pragma unroll
        for (int i = 0; i < 4; ++i) af[i] = *(const bf16x8*)&As[cur][wm + i * 16 + col][quad * 8];
#pragma unroll
        for (int j = 0; j < 4; ++j) bfr[j] = *(const bf16x8*)&Bs[cur][wn + j * 16 + col][quad * 8];
#pragma unroll
        for (int i = 0; i < 4; ++i)
#pragma unroll
            for (int j = 0; j < 4; ++j)
                acc[i][j] = __builtin_amdgcn_mfma_f32_16x16x32_bf16(af[i], bfr[j], acc[i][j], 0, 0, 0);
    }
#pragma unroll
    for (int i = 0; i < 4; ++i)
#pragma unroll
        for (int j = 0; j < 4; ++j)
#pragma unroll
            for (int r = 0; r < 4; ++r)
                C[(size_t)(bm + wm + i * 16 + quad * 4 + r) * 1024 + bn + wn + j * 16 + col] =
                    acc[i][j][r];
}

// ---------------------------------------------------------------------------
// MFMA flash attention v5 — 4 q-sets per wave (64 q-rows), 2-wave blocks.
// Each staged K/V tile feeds 4x the MFMA of v4: LDS bytes per FLOP halved.
// Register-chained P (no LDS round-trip), chunk-offset pipeline:
// iter ch runs PV(ch-1) + S(ch) as back-to-back MFMA bursts, then exp2/pack.
// 1 wave/SIMD at ~300 VGPR saturates the matrix pipe m06-style.
// ---------------------------------------------------------------------------
__global__ __launch_bounds__(128, 1) void attn_mfma(
    const u16* __restrict__ QKV, u16* __restrict__ AO)
{
    __shared__ u16 Ks[2][128][64];   // [key][dim], unpadded, XOR-swizzled 16B blocks
    __shared__ u16 Vt[2][64][136];   // [dim][key], key-pairs packed in dwords
    const int bid = blockIdx.x;
    int h, qt;
    if (bid < 256) { h = 8 + (bid & 7); qt = bid >> 3; }           // diff: 32 chunks
    else { int i = bid - 256; h = i & 7; qt = 31 - (i >> 3); }     // causal desc qt
    const bool causal = (h < NAR);
    const int tid = threadIdx.x;
    const int w = tid >> 6, lane = tid & 63;
    const int col = lane & 15, quad = lane >> 4;
    const int qb = qt * 128;
    const int qr0 = qb + w * 64 + col;   // q-set s row = qr0 + s*16

    // hoisted Q B-frags (rope'd, pre-scaled by 0.125*log2e in gemm_qkv)
    bf16x8 qf[4][2];
#pragma unroll
    for (int s = 0; s < 4; ++s)
#pragma unroll
        for (int ks = 0; ks < 2; ++ks)
            qf[s][ks] = *(const bf16x8*)(QKV + (size_t)(qr0 + s * 16) * QKVS +
                                         h * DHEAD + ks * 32 + quad * 8);

    bf16x4 ones;
    ones[0] = (short)0x3F80; ones[1] = (short)0x3F80;
    ones[2] = (short)0x3F80; ones[3] = (short)0x3F80;

    const f32x4 zero = {0.f, 0.f, 0.f, 0.f};
    f32x4 O[4][5];  // [set][nd] O^T tiles (d = nd*16+quad*4+r, q = col); nd=4 = l
#pragma unroll
    for (int s = 0; s < 4; ++s)
#pragma unroll
        for (int nd = 0; nd < 5; ++nd) O[s][nd] = zero;

    const int nch = causal ? (qt + 1) : (LSEQ / 128);
    // cp16 K addressing: 8 rows/issue, XOR-swizzled col block; 8 issues/wave
    const int krow = lane >> 3;
    const int kcb = (lane & 7) ^ krow;
    const u16* kbase = QKV + (size_t)krow * QKVS + 1024 + h * DHEAD + kcb * 8;
    // V staging: thread covers key rows 2*lane, 2*lane+1, dims w*32..w*32+31
    const u16* vbase = QKV + (size_t)(lane * 2) * QKVS + 2048 + h * DHEAD + w * 32;

    u32x4 vA[4], vB[4];   // pending V(ch): A = even key row, B = odd; 8 dims each
    bf16x4 pf[4][8];      // P(ch) frags, consumed by PV at iter ch+1

#define VT_WRITE(buf)                                                                     \
    {                                                                                     \
        _Pragma("unroll")                                                                 \
        for (int part = 0; part < 4; ++part)                                              \
            _Pragma("unroll")                                                             \
            for (int j = 0; j < 4; ++j) {                                                 \
                const int d = w * 32 + part * 8 + 2 * j;                                  \
                *(u32*)&Vt[buf][d][lane * 2] =                                            \
                    __builtin_amdgcn_perm(vB[part][j], vA[part][j], 0x05040100u);         \
                *(u32*)&Vt[buf][d + 1][lane * 2] =                                        \
                    __builtin_amdgcn_perm(vB[part][j], vA[part][j], 0x07060302u);         \
            }                                                                             \
    }

#define V_LOAD(chbase)                                                                    \
    {                                                                                     \
        const u16* vp = vbase + (size_t)(chbase) * QKVS;                                  \
        _Pragma("unroll")                                                                 \
        for (int part = 0; part < 4; ++part) {                                            \
            vA[part] = *(u32x4*)(vp + part * 8);                                          \
            vB[part] = *(u32x4*)(vp + QKVS + part * 8);                                   \
        }                                                                                 \
    }

#define K_STAGE(chbase, buf)                                                              \
    {                                                                                     \
        _Pragma("unroll")                                                                 \
        for (int i = 0; i < 8; ++i) {                                                     \
            const int j = i * 2 + w;                                                      \
            cp16(kbase + (size_t)((chbase) + j * 8) * QKVS, &Ks[buf][j * 8][0]);          \
        }                                                                                 \
    }

#define S_EXP(buf, chq)                                                                   \
    {                                                                                     \
        const bool mask = causal && ((chq) == qt);                                        \
        _Pragma("unroll")                                                                 \
        for (int hf = 0; hf < 2; ++hf) {                                                  \
            f32x4 st[4][4];                                                               \
            _Pragma("unroll")                                                             \
            for (int s = 0; s < 4; ++s)                                                   \
                _Pragma("unroll")                                                         \
                for (int jj = 0; jj < 4; ++jj) st[s][jj] = zero;                          \
            _Pragma("unroll")                                                             \
            for (int jj = 0; jj < 4; ++jj)                                                \
                _Pragma("unroll")                                                         \
                for (int ks = 0; ks < 2; ++ks) {                                          \
                    bf16x8 kf = *(const bf16x8*)&Ks[buf][(hf * 4 + jj) * 16 + col]        \
                                                    [((ks * 4 + quad) ^ (col & 7)) * 8];  \
                    _Pragma("unroll")                                                     \
                    for (int s = 0; s < 4; ++s)                                           \
                        st[s][jj] = __builtin_amdgcn_mfma_f32_16x16x32_bf16(              \
                            kf, qf[s][ks], st[s][jj], 0, 0, 0);                           \
                }                                                                         \
            if (mask) {                                                                   \
                _Pragma("unroll")                                                         \
                for (int jj = 0; jj < 4; ++jj) {                                          \
                    const int kk = (chq) * 128 + (hf * 4 + jj) * 16 + quad * 4;           \
                    _Pragma("unroll")                                                     \
                    for (int s = 0; s < 4; ++s)                                           \
                        _Pragma("unroll")                                                 \
                        for (int r = 0; r < 4; ++r)                                       \
                            if (kk + r > qr0 + s * 16) st[s][jj][r] = -1e30f;             \
                }                                                                         \
            }                                                                             \
            _Pragma("unroll")                                                             \
            for (int s = 0; s < 4; ++s)                                                   \
                _Pragma("unroll")                                                         \
                for (int jj = 0; jj < 4; ++jj) {                                          \
                    u32 lo = packtr(__builtin_amdgcn_exp2f(st[s][jj][0]),                 \
                                    __builtin_amdgcn_exp2f(st[s][jj][1]));                \
                    u32 hi = packtr(__builtin_amdgcn_exp2f(st[s][jj][2]),                 \
                                    __builtin_amdgcn_exp2f(st[s][jj][3]));                \
                    u32* p = (u32*)&pf[s][hf * 4 + jj];                                   \
                    p[0] = lo; p[1] = hi;                                                 \
                }                                                                         \
        }                                                                                 \
    }

#define PV(buf)                                                                           \
    {                                                                                     \
        _Pragma("unroll")                                                                 \
        for (int nd = 0; nd < 4; ++nd)                                                    \
            _Pragma("unroll")                                                             \
            for (int t = 0; t < 8; ++t) {                                                 \
                bf16x4 vtf = *(const bf16x4*)&Vt[buf][nd * 16 + col][t * 16 + quad * 4];  \
                _Pragma("unroll")                                                         \
                for (int s = 0; s < 4; ++s)                                               \
                    O[s][nd] = __builtin_amdgcn_mfma_f32_16x16x16bf16_1k(                 \
                        vtf, pf[s][t], O[s][nd], 0, 0, 0);                                \
            }                                                                             \
        _Pragma("unroll")                                                                 \
        for (int t = 0; t < 8; ++t)                                                       \
            _Pragma("unroll")                                                             \
            for (int s = 0; s < 4; ++s)                                                   \
                O[s][4] = __builtin_amdgcn_mfma_f32_16x16x16bf16_1k(                      \
                    ones, pf[s][t], O[s][4], 0, 0, 0);                                    \
    }

    // ---- prologue: stage chunk 0 ----
    K_STAGE(0, 0);
    V_LOAD(0);
    __syncthreads();  // cp16(0) drained
    VT_WRITE(0);
    if (nch > 1) {
        K_STAGE(128, 1);
        V_LOAD(128);
    }
    S_EXP(0, 0);

    // ---- main loop: PV(ch-1) + S(ch) per iteration ----
    for (int ch = 1; ch < nch; ++ch) {
        const int cur = ch & 1, prv = cur ^ 1;
        __syncthreads();  // Ks[cur] staged; Vt[prv] visible; Vt[cur] free
        VT_WRITE(cur);
        if (ch + 1 < nch) {
            K_STAGE((ch + 1) * 128, prv);
            V_LOAD((size_t)(ch + 1) * 128);
        }
        PV(prv);          // PV(ch-1): independent of S(ch) — fused MFMA burst
        S_EXP(cur, ch);   // S(ch) + exp -> pf
    }

    // ---- tail: PV(nch-1) ----
    __syncthreads();
    PV((nch - 1) & 1);

    // epilogue: l already in this lane (col=q); O^T rows d = nd*16+quad*4+r
#pragma unroll
    for (int s = 0; s < 4; ++s) {
        const float inv = 1.f / O[s][4][0];
        const int qrow = qr0 + s * 16;
#pragma unroll
        for (int nd = 0; nd < 4; ++nd) {
            ushort4 ov;
            ov.x = f2bf(O[s][nd][0] * inv);
            ov.y = f2bf(O[s][nd][1] * inv);
            ov.z = f2bf(O[s][nd][2] * inv);
            ov.w = f2bf(O[s][nd][3] * inv);
            *(ushort4*)(AO + (size_t)qrow * 1024 + h * DHEAD + nd * 16 + quad * 4) = ov;
        }
    }
#undef VT_WRITE
#undef V_LOAD
#undef K_STAGE
#undef S_EXP
#undef PV
}

// ---------------------------------------------------------------------------
extern "C" void kernel_launch(void* const* d_in, const int* in_sizes, int n_in,
                              void* d_out, int out_size, void* d_ws, size_t ws_size,
                              hipStream_t stream)
{
    const float* X  = (const float*)d_in[0];
    const float* Wq = (const float*)d_in[1];
    const float* Wk = (const float*)d_in[2];
    const float* Wv = (const float*)d_in[3];
    const float* Wo = (const float*)d_in[4];
    float* out = (float*)d_out;

    // ws (u16 units), liveness overlays:
    //   [0 .. 4M):   Wqkvt [3072][1024] (dead after gemm_qkv) -> AOb [4096][1024]
    //   [4M .. 16M): QKV [4096][3072] (dead after attn) -> Wot [1024][1024]
    u16* Wt  = (u16*)d_ws;
    u16* AOb = (u16*)d_ws;
    u16* QKV = (u16*)d_ws + (size_t)4 * 1024 * 1024;
    u16* Wot = QKV;

    transp_cvt3<<<dim3(16, 16, 3), 256, 0, stream>>>(Wq, Wk, Wv, Wt);
    gemm_qkv<<<dim3(24, 32), 256, 0, stream>>>(X, Wt, QKV);   // rope fused in epilogue
    attn_mfma<<<512, 128, 0, stream>>>(QKV, AOb);
    transp_cvt<<<dim3(16, 16), 256, 0, stream>>>(Wo, Wot);    // QKV dead now
    gemm_out<<<dim3(8, 32), 256, 0, stream>>>(AOb, Wot, out);
}